// Round 9
// baseline (858.191 us; speedup 1.0000x reference)
//
#include <hip/hip_runtime.h>

// BiGRU, B=512, T=512, D=16, H=64 — MFMA recurrence, latency-optimized.
// Backward direction needs only ONE cell step (ys_b[0] = GRUCell(x[:,T-1,:], 0)).
//
// R8 lesson: correct MFMA version (absmax 3e-5) but ~1880 of 2076 cyc/step is
// stall (MfmaUtil 2.5%, VALUBusy 7%): per-step global x load + h LDS round
// trip + 9-deep MFMA chains, nothing to fill them. Latency-bound: CU count
// irrelevant; only per-step latency + stall-filling matter.
//
// This version:
//  - x staged per 32-step chunk into LDS as bf16 hi/lo PLANES indexed by t;
//    kt=2 B-frag reads planes directly (q<2) -> zero per-step global traffic,
//    s holds only h (kt 0,1).
//  - TWO independent 16-batch groups per block (32 batches/block, 16 blocks):
//    shared A-frags (same weights), interleaved B/acc/gates -> the second
//    chain fills the first chain's stalls (R6 proved in-wave ILP works).
//  - hi/lo bf16 split: D += Whi*shi + Whi*slo + Wlo*shi (fp32-equivalent).
//  - one barrier/step (parity-dbuf s), gates fully in registers.

typedef unsigned int uint32;
typedef unsigned short u16;
typedef __attribute__((ext_vector_type(8))) short bf16x8;
typedef __attribute__((ext_vector_type(4))) float f32x4;

#define Hh 64
#define Dd 16
#define Tt 512
#define Bb 512
#define NG 2      // batch groups per block
#define NBat 16   // batches per group
#define CH 32     // timesteps per x chunk
#define SROW 72   // ushorts per s row (64 h + 8 pad) = 144 B (16B-aligned, 2-way max)
#define XROW 24   // ushorts per xs row (16 x + 8 pad) = 48 B

__device__ __forceinline__ u16 f2bf(float f) {
    uint32 u = __float_as_uint(f);
    return (u16)((u + 0x7FFFu + ((u >> 16) & 1u)) >> 16);
}
__device__ __forceinline__ float bf2f(u16 h) {
    return __uint_as_float(((uint32)h) << 16);
}
__device__ __forceinline__ float sigmoid_fast(float v) {
    return 1.0f / (1.0f + __expf(-v));
}
__device__ __forceinline__ float tanh_fast(float v) {
    float e = __expf(2.0f * v);
    return 1.0f - 2.0f / (e + 1.0f);
}
__device__ __forceinline__ f32x4 mfma16(bf16x8 a, bf16x8 b, f32x4 c) {
    return __builtin_amdgcn_mfma_f32_16x16x32_bf16(a, b, c, 0, 0, 0);
}
__device__ __forceinline__ float dot4(float4 a, float4 b) {
    return a.x * b.x + a.y * b.y + a.z * b.z + a.w * b.w;
}

// A-fragment (hi+lo) for augmented row `row`, K-tile kt.
// mode 0 = r/z (W_hh k<64, W_ih k 64..80), 1 = nh (W_hh only), 2 = nx (W_ih only).
__device__ __forceinline__ void build_frag(const float* __restrict__ w_hh,
                                           const float* __restrict__ w_ih,
                                           int row, int kt, int lane, int mode,
                                           bf16x8* fhi, bf16x8* flo) {
    const int kbase = kt * 32 + (lane >> 4) * 8;
    bf16x8 hi, lo;
#pragma unroll
    for (int i = 0; i < 8; ++i) {
        int k = kbase + i;
        float f = 0.0f;
        if (mode == 0) {
            if (k < 64)      f = w_hh[row * 64 + k];
            else if (k < 80) f = w_ih[row * 16 + (k - 64)];
        } else if (mode == 1) {
            if (k < 64)      f = w_hh[row * 64 + k];
        } else {
            if (k >= 64 && k < 80) f = w_ih[row * 16 + (k - 64)];
        }
        u16 h  = f2bf(f);
        u16 l2 = f2bf(f - bf2f(h));
        hi[i] = (short)h;
        lo[i] = (short)l2;
    }
    *fhi = hi; *flo = lo;
}

__global__ __launch_bounds__(256, 1)
void bigru_mfma2_kernel(const float* __restrict__ x,
                        const float* __restrict__ w_ih_f, const float* __restrict__ w_hh_f,
                        const float* __restrict__ b_ih_f, const float* __restrict__ b_hh_f,
                        const float* __restrict__ w_ih_b, const float* __restrict__ w_hh_b,
                        const float* __restrict__ b_ih_b, const float* __restrict__ b_hh_b,
                        const float* __restrict__ fc_w,  const float* __restrict__ fc_b,
                        float* __restrict__ out)
{
    const int tid = threadIdx.x;
    const int l   = tid & 63;
    const int w   = tid >> 6;       // wave 0..3 -> j slice
    const int q   = l >> 4;         // quad
    const int bc  = l & 15;         // batch column within group
    const int bbase = blockIdx.x * (NG * NBat);   // 32 batches per block

    __shared__ __align__(16) u16 s_hi[2][NG][NBat][SROW];     // 9.2 KB
    __shared__ __align__(16) u16 s_lo[2][NG][NBat][SROW];     // 9.2 KB
    __shared__ __align__(16) u16 xs_hi[CH][NG][NBat][XROW];   // 49 KB
    __shared__ __align__(16) u16 xs_lo[CH][NG][NBat][XROW];   // 49 KB
    __shared__ __align__(16) float hfin[NG * NBat][68];       // 8.7 KB

    // ---- zero h state buffers (both parities) ----
    {
        uint32* p1 = (uint32*)s_hi;
        uint32* p2 = (uint32*)s_lo;
        const int n32 = 2 * NG * NBat * SROW / 2;   // 2304 dwords each
        for (int i = tid; i < n32; i += 256) { p1[i] = 0u; p2[i] = 0u; }
    }

    // ---- A-fragments (hi/lo) for this wave's 16-row j slice, built once ----
    const int jb   = 16 * w;
    const int mrow = jb + bc;       // A row index within each gate block
    bf16x8 Ar_h[3], Ar_l[3], Az_h[3], Az_l[3], Anh_h[2], Anh_l[2], Anx_h, Anx_l;
#pragma unroll
    for (int kt = 0; kt < 3; ++kt) {
        build_frag(w_hh_f, w_ih_f, mrow,      kt, l, 0, &Ar_h[kt], &Ar_l[kt]);
        build_frag(w_hh_f, w_ih_f, 64 + mrow, kt, l, 0, &Az_h[kt], &Az_l[kt]);
    }
#pragma unroll
    for (int kt = 0; kt < 2; ++kt)
        build_frag(w_hh_f, w_ih_f, 128 + mrow, kt, l, 1, &Anh_h[kt], &Anh_l[kt]);
    build_frag(w_hh_f, w_ih_f, 128 + mrow, 2, l, 2, &Anx_h, &Anx_l);

    // ---- per-lane biases for C rows j = jc..jc+3, and h state per group ----
    const int jc = jb + q * 4;
    float br[4], bz[4], bxn[4], bhn[4], h[NG][4];
#pragma unroll
    for (int r2 = 0; r2 < 4; ++r2) {
        int j = jc + r2;
        br[r2]  = b_ih_f[j]        + b_hh_f[j];
        bz[r2]  = b_ih_f[64 + j]   + b_hh_f[64 + j];
        bxn[r2] = b_ih_f[128 + j];
        bhn[r2] = b_hh_f[128 + j];
        h[0][r2] = 0.0f; h[1][r2] = 0.0f;
    }

    for (int tc = 0; tc < Tt / CH; ++tc) {
        // ---- stage x chunk: 32 t x 32 batches x 16 d, coalesced, split hi/lo ----
#pragma unroll 4
        for (int i = 0; i < 16; ++i) {
            int f    = i * 256 + tid;     // 0..4095 float4 index within chunk
            int bsel = f >> 7;            // 0..31 (g*16 + bb)
            int rem  = f & 127;
            int t    = rem >> 2;          // 0..31
            int f4   = rem & 3;
            float4 v = ((const float4*)x)[(size_t)(bbase + bsel) * (Tt * Dd / 4)
                                          + (size_t)(tc * CH + t) * (Dd / 4) + f4];
            u16 h0 = f2bf(v.x), h1 = f2bf(v.y), h2 = f2bf(v.z), h3 = f2bf(v.w);
            u16 l0 = f2bf(v.x - bf2f(h0)), l1 = f2bf(v.y - bf2f(h1));
            u16 l2 = f2bf(v.z - bf2f(h2)), l3 = f2bf(v.w - bf2f(h3));
            uint2 ph, pl;
            ph.x = (uint32)h0 | ((uint32)h1 << 16);
            ph.y = (uint32)h2 | ((uint32)h3 << 16);
            pl.x = (uint32)l0 | ((uint32)l1 << 16);
            pl.y = (uint32)l2 | ((uint32)l3 << 16);
            int g = bsel >> 4, bb2 = bsel & 15;
            *(uint2*)&xs_hi[t][g][bb2][f4 * 4] = ph;
            *(uint2*)&xs_lo[t][g][bb2][f4 * 4] = pl;
        }
        __syncthreads();   // staging visible (also covers s zero-init / prev chunk)

        for (int tt = 0; tt < CH; ++tt) {
            const int t = tc * CH + tt;
            const int par = t & 1, parn = par ^ 1;

            // ---- B-fragments: h from s (kt 0,1), x from planes (kt 2) ----
            bf16x8 Bh[NG][3], Bl[NG][3];
#pragma unroll
            for (int g = 0; g < NG; ++g) {
                Bh[g][0] = *(const bf16x8*)&s_hi[par][g][bc][q * 8];
                Bl[g][0] = *(const bf16x8*)&s_lo[par][g][bc][q * 8];
                Bh[g][1] = *(const bf16x8*)&s_hi[par][g][bc][32 + q * 8];
                Bl[g][1] = *(const bf16x8*)&s_lo[par][g][bc][32 + q * 8];
                bf16x8 zx = {0,0,0,0,0,0,0,0};
                bf16x8 zl = {0,0,0,0,0,0,0,0};
                if (q < 2) {
                    zx = *(const bf16x8*)&xs_hi[tt][g][bc][q * 8];
                    zl = *(const bf16x8*)&xs_lo[tt][g][bc][q * 8];
                }
                Bh[g][2] = zx;
                Bl[g][2] = zl;
            }

            // ---- MFMA: 27 per group, 2 groups interleaved by the scheduler ----
            f32x4 ar[NG], az[NG], anh[NG], anx[NG];
#pragma unroll
            for (int g = 0; g < NG; ++g) {
                ar[g] = (f32x4){0,0,0,0}; az[g] = (f32x4){0,0,0,0};
                anh[g] = (f32x4){0,0,0,0}; anx[g] = (f32x4){0,0,0,0};
#pragma unroll
                for (int kt = 0; kt < 3; ++kt) {
                    ar[g] = mfma16(Ar_h[kt], Bh[g][kt], ar[g]);
                    ar[g] = mfma16(Ar_h[kt], Bl[g][kt], ar[g]);
                    ar[g] = mfma16(Ar_l[kt], Bh[g][kt], ar[g]);
                    az[g] = mfma16(Az_h[kt], Bh[g][kt], az[g]);
                    az[g] = mfma16(Az_h[kt], Bl[g][kt], az[g]);
                    az[g] = mfma16(Az_l[kt], Bh[g][kt], az[g]);
                }
#pragma unroll
                for (int kt = 0; kt < 2; ++kt) {
                    anh[g] = mfma16(Anh_h[kt], Bh[g][kt], anh[g]);
                    anh[g] = mfma16(Anh_h[kt], Bl[g][kt], anh[g]);
                    anh[g] = mfma16(Anh_l[kt], Bh[g][kt], anh[g]);
                }
                anx[g] = mfma16(Anx_h, Bh[g][2], anx[g]);
                anx[g] = mfma16(Anx_h, Bl[g][2], anx[g]);
                anx[g] = mfma16(Anx_l, Bh[g][2], anx[g]);
            }

            // ---- gates in registers, write h hi/lo packed ----
#pragma unroll
            for (int g = 0; g < NG; ++g) {
                u16 hh[4], hl[4];
#pragma unroll
                for (int r2 = 0; r2 < 4; ++r2) {
                    float rg = sigmoid_fast(ar[g][r2] + br[r2]);
                    float zg = sigmoid_fast(az[g][r2] + bz[r2]);
                    float ng = tanh_fast(anx[g][r2] + bxn[r2] + rg * (anh[g][r2] + bhn[r2]));
                    h[g][r2] = ng + zg * (h[g][r2] - ng);
                    u16 hb16 = f2bf(h[g][r2]);
                    hh[r2] = hb16;
                    hl[r2] = f2bf(h[g][r2] - bf2f(hb16));
                }
                uint2 ph, pl;
                ph.x = (uint32)hh[0] | ((uint32)hh[1] << 16);
                ph.y = (uint32)hh[2] | ((uint32)hh[3] << 16);
                pl.x = (uint32)hl[0] | ((uint32)hl[1] << 16);
                pl.y = (uint32)hl[2] | ((uint32)hl[3] << 16);
                *(uint2*)&s_hi[parn][g][bc][jc] = ph;
                *(uint2*)&s_lo[parn][g][bc][jc] = pl;
            }
            __syncthreads();
        }
    }

    // ---- publish final forward h ----
#pragma unroll
    for (int g = 0; g < NG; ++g)
        *(float4*)&hfin[g * NBat + bc][jc] = make_float4(h[g][0], h[g][1], h[g][2], h[g][3]);
    __syncthreads();

    // ---- backward single cell step + fused FC: wave w handles batches 8w..8w+7 ----
    {
        const int j = l;
        float4 wq0[4], wq1[4], wq2[4];
        {
            const float4* p0 = (const float4*)(w_ih_b + (size_t)j         * Dd);
            const float4* p1 = (const float4*)(w_ih_b + (size_t)(64 + j)  * Dd);
            const float4* p2 = (const float4*)(w_ih_b + (size_t)(128 + j) * Dd);
#pragma unroll
            for (int qq = 0; qq < 4; ++qq) { wq0[qq] = p0[qq]; wq1[qq] = p1[qq]; wq2[qq] = p2[qq]; }
        }
        const float brb  = b_ih_b[j]        + b_hh_b[j];
        const float bzb  = b_ih_b[64 + j]   + b_hh_b[64 + j];
        const float bxnb = b_ih_b[128 + j];
        const float bhnb = b_hh_b[128 + j];
        const float fw1 = fc_w[j], fw2 = fc_w[64 + j];

#pragma unroll
        for (int p = 0; p < 8; ++p) {
            const int bl = 8 * w + p;           // 0..31
            const float4* xl = (const float4*)(x + ((size_t)(bbase + bl) * Tt + (Tt - 1)) * Dd);
            float ar2 = brb, az2 = bzb, axn2 = bxnb;
#pragma unroll
            for (int qq = 0; qq < 4; ++qq) {
                float4 xv = xl[qq];
                ar2  += dot4(wq0[qq], xv);
                az2  += dot4(wq1[qq], xv);
                axn2 += dot4(wq2[qq], xv);
            }
            float rb = sigmoid_fast(ar2);
            float zb = sigmoid_fast(az2);
            float nb = tanh_fast(axn2 + rb * bhnb);
            float hb = (1.0f - zb) * nb;        // h0 = 0

            float v = fw1 * hfin[bl][j] + fw2 * hb;
#pragma unroll
            for (int off = 32; off > 0; off >>= 1)
                v += __shfl_xor(v, off, 64);
            if (j == 0) out[bbase + bl] = v + fc_b[0];
        }
    }
}

extern "C" void kernel_launch(void* const* d_in, const int* in_sizes, int n_in,
                              void* d_out, int out_size, void* d_ws, size_t ws_size,
                              hipStream_t stream) {
    const float* x      = (const float*)d_in[0];
    const float* w_ih_f = (const float*)d_in[1];
    const float* w_hh_f = (const float*)d_in[2];
    const float* b_ih_f = (const float*)d_in[3];
    const float* b_hh_f = (const float*)d_in[4];
    const float* w_ih_b = (const float*)d_in[5];
    const float* w_hh_b = (const float*)d_in[6];
    const float* b_ih_b = (const float*)d_in[7];
    const float* b_hh_b = (const float*)d_in[8];
    const float* fc_w   = (const float*)d_in[9];
    const float* fc_b   = (const float*)d_in[10];

    bigru_mfma2_kernel<<<dim3(Bb / (NG * NBat)), dim3(256), 0, stream>>>(
        x, w_ih_f, w_hh_f, b_ih_f, b_hh_f,
        w_ih_b, w_hh_b, b_ih_b, b_hh_b, fc_w, fc_b,
        (float*)d_out);
}